// Round 2
// baseline (247.333 us; speedup 1.0000x reference)
//
#include <hip/hip_runtime.h>

#define BB 16
#define CC 256
#define NN 4096
#define CN (CC*NN)
#define GG 8
#define EPSF 1e-8f

// ---------------- transpose conv_w -> wT[c][d] (so conv reads are wave-uniform) -------------
__global__ __launch_bounds__(256) void k_wt(const float* __restrict__ conv_w,
                                            float* __restrict__ wT) {
  int o = blockIdx.x * 256 + threadIdx.x;  // 16384
  int d = o >> 8, c = o & 255;
  wT[c * 64 + d] = conv_w[d * 256 + c];
}

// ---------------- conv(1x1)+relu+pool partials + x passthrough ------------------------------
// grid: 16 b x 64 n-chunks(64). block: 256 thr = 64 n (lane) x 4 d-quarters (wave).
// Each thread: acc[16] over its d-range, loop all 256 c. Weight reads wave-uniform (s_load).
// Wave wv writes the x-passthrough slice c in [wv*64, wv*64+64). 4 blk/CU = 16 waves/CU.
__global__ __launch_bounds__(256) void k_conv(const float* __restrict__ x,
                                              const float* __restrict__ wT,
                                              const float* __restrict__ conv_b,
                                              float* __restrict__ pooledpart,
                                              float* __restrict__ xout) {
  const int b = blockIdx.x >> 6;
  const int chunk = blockIdx.x & 63;
  const int t = threadIdx.x;
  const int lane = t & 63;          // n within chunk
  const int wv = t >> 6;            // d-quarter
  const int d0 = wv * 16;
  const size_t base = (size_t)b * CN + chunk * 64 + lane;
  const float* xp = x + base;
  float* xo = xout + base;
  float acc[16];
#pragma unroll
  for (int i = 0; i < 16; ++i) acc[i] = 0.f;
  const int clo = wv * 64, chi = clo + 64;
#pragma unroll 4
  for (int c = 0; c < 256; ++c) {
    float xv = xp[(size_t)c * NN];
    if (c >= clo && c < chi) xo[(size_t)c * NN] = xv;  // wave-uniform predicate
    const float* wc = wT + c * 64 + d0;  // uniform address -> s_load
#pragma unroll
    for (int i = 0; i < 16; ++i) acc[i] = fmaf(wc[i], xv, acc[i]);
  }
  const float* cb = conv_b + d0;  // uniform
#pragma unroll
  for (int i = 0; i < 16; ++i) {
    float h = fmaxf(acc[i] + cb[i], 0.f);
#pragma unroll
    for (int off = 1; off < 64; off <<= 1) h += __shfl_xor(h, off, 64);
    acc[i] = h;
  }
  if (lane == 0) {
    float* pp = pooledpart + ((size_t)b * 64 + chunk) * 64 + d0;
#pragma unroll
    for (int i = 0; i < 16; ++i) pp[i] = acc[i];
  }
}

// ---------------- x row norms ---------------------------------------------------------------
__global__ __launch_bounds__(256) void k_xnorm(const float* __restrict__ x,
                                               float* __restrict__ xnorm) {
  const int bc = blockIdx.x;  // b*256+c
  const float4* xr = (const float4*)(x + (size_t)bc * NN);
  const int t = threadIdx.x;
  float s = 0.f;
#pragma unroll
  for (int j = 0; j < 4; ++j) {
    float4 v = xr[t + j * 256];
    s += v.x * v.x + v.y * v.y + v.z * v.z + v.w * v.w;
  }
#pragma unroll
  for (int off = 1; off < 64; off <<= 1) s += __shfl_xor(s, off, 64);
  __shared__ float red[4];
  if ((t & 63) == 0) red[t >> 6] = s;
  __syncthreads();
  if (t == 0) {
    float nrm = sqrtf(red[0] + red[1] + red[2] + red[3]);
    xnorm[bc] = fmaxf(nrm, EPSF);
  }
}

// ---------------- pooled-reduce + logits + log(ga) + softmax -> wg --------------------------
__global__ __launch_bounds__(256) void k_logits(const float* __restrict__ pooledpart,
                                                const float* __restrict__ lin_w,
                                                const float* __restrict__ lin_b,
                                                const float* __restrict__ ga,
                                                float* __restrict__ logits,
                                                float* __restrict__ wg) {
  const int b = blockIdx.x, t = threadIdx.x;
  __shared__ float ps[64];
  if (t < 64) {
    float s = 0.f;
#pragma unroll 8
    for (int k = 0; k < 64; ++k) s += pooledpart[((size_t)b * 64 + k) * 64 + t];
    ps[t] = s * (1.f / 4096.f);
  }
  __syncthreads();
  const int c = t;
  float out[8];
#pragma unroll
  for (int g = 0; g < 8; ++g) {
    const float4* wr = (const float4*)(lin_w + ((size_t)c * 8 + g) * 64);
    float s = 0.f;
#pragma unroll
    for (int k4 = 0; k4 < 16; ++k4) {
      float4 wv = wr[k4];
      s += wv.x * ps[k4 * 4] + wv.y * ps[k4 * 4 + 1] + wv.z * ps[k4 * 4 + 2] +
           wv.w * ps[k4 * 4 + 3];
    }
    out[g] = s + lin_b[c * 8 + g] + logf(ga[((size_t)b * 256 + c) * 8 + g] + EPSF);
  }
  float* lp = logits + ((size_t)b * 256 + c) * 8;
  *(float4*)lp = make_float4(out[0], out[1], out[2], out[3]);
  *(float4*)(lp + 4) = make_float4(out[4], out[5], out[6], out[7]);
  // softmax -> wg
  float m = out[0];
#pragma unroll
  for (int g = 1; g < 8; ++g) m = fmaxf(m, out[g]);
  float sum = 0.f;
#pragma unroll
  for (int g = 0; g < 8; ++g) { out[g] = __expf(out[g] - m); sum += out[g]; }
  float r = 1.f / sum;
  float4* op = (float4*)(wg + ((size_t)b * 256 + c) * 8);
  op[0] = make_float4(out[0] * r, out[1] * r, out[2] * r, out[3] * r);
  op[1] = make_float4(out[4] * r, out[5] * r, out[6] * r, out[7] * r);
}

// ---------------- s[b][g][n] = sum_c w[b][c][g] * x[b][c][n]  (+ s^2 partials) --------------
// grid: 16 b x 32 n-chunks(128). thread: 2 n (float2), 8 g; waves split c 4-ways.
__global__ __launch_bounds__(256) void k_s(const float* __restrict__ x,
                                           const float* __restrict__ wg,
                                           float* __restrict__ s,
                                           float* __restrict__ spart2) {
  const int b = blockIdx.x >> 5, nt = blockIdx.x & 31;
  const int t = threadIdx.x;
  const int nl = t & 63;
  const int cq = __builtin_amdgcn_readfirstlane(t >> 6);
  const int n0 = nt * 128;
  float ax[8], ay[8];
#pragma unroll
  for (int g = 0; g < 8; ++g) { ax[g] = 0.f; ay[g] = 0.f; }
  const float* wb = wg + (size_t)b * 2048 + cq * 512;  // uniform -> s_load
  const float* xb = x + (size_t)b * CN + (size_t)(cq * 64) * NN + n0 + nl * 2;
#pragma unroll 4
  for (int cc = 0; cc < 64; ++cc) {
    const float2 xv = *(const float2*)(xb + (size_t)cc * NN);
    const float* wc = wb + cc * 8;
#pragma unroll
    for (int g = 0; g < 8; ++g) {
      ax[g] = fmaf(wc[g], xv.x, ax[g]);
      ay[g] = fmaf(wc[g], xv.y, ay[g]);
    }
  }
  __shared__ float part[4][8][128];
#pragma unroll
  for (int g = 0; g < 8; ++g) {
    part[cq][g][nl * 2] = ax[g];
    part[cq][g][nl * 2 + 1] = ay[g];
  }
  __syncthreads();
  float* sb = s + (size_t)b * 8 * NN + n0;
#pragma unroll
  for (int k = 0; k < 2; ++k) {
    int f2 = k * 256 + t;
    int g = f2 >> 6, np = f2 & 63;
    float vx = part[0][g][np * 2] + part[1][g][np * 2] + part[2][g][np * 2] + part[3][g][np * 2];
    float vy = part[0][g][np * 2 + 1] + part[1][g][np * 2 + 1] + part[2][g][np * 2 + 1] +
               part[3][g][np * 2 + 1];
    *(float2*)(sb + (size_t)g * NN + np * 2) = make_float2(vx, vy);
    float s2 = vx * vx + vy * vy;
#pragma unroll
    for (int off = 1; off < 64; off <<= 1) s2 += __shfl_xor(s2, off, 64);
    if ((t & 63) == 0) spart2[((size_t)b * 32 + nt) * 8 + g] = s2;
  }
}

// ---------------- sim partials: simpart[b][nt][c][g] = sum_{n in chunk} x*s ------------------
// grid: 16 b x 16 n-chunks(256) x 4 c-quarters(64). LDS-staged x tile, 8c x 8g per thread.
__global__ __launch_bounds__(256) void k_sim(const float* __restrict__ x,
                                             const float* __restrict__ s,
                                             float* __restrict__ simpart) {
  const int blk = blockIdx.x;
  const int cq = blk & 3, nt = (blk >> 2) & 15, b = blk >> 6;
  const int t = threadIdx.x;
  const int n0 = nt * 256, c0 = cq * 64;
  __shared__ float xs[64][260];    // 260-f32 row stride: 16B-aligned, spreads banks
  __shared__ float slbuf[8][260];  // s tile; reused as reduce pool after barrier
  {
    const float* xb = x + (size_t)b * CN + (size_t)c0 * NN + n0;
#pragma unroll
    for (int k = 0; k < 16; ++k) {
      int f = k * 256 + t;
      int r = f >> 6, j = f & 63;
      float4 v = *(const float4*)(xb + (size_t)r * NN + j * 4);
      *(float4*)&xs[r][j * 4] = v;
    }
    const float* sb = s + (size_t)b * 8 * NN + n0;
#pragma unroll
    for (int k = 0; k < 2; ++k) {
      int f = k * 256 + t;
      int g = f >> 6, j = f & 63;
      float4 v = *(const float4*)(sb + (size_t)g * NN + j * 4);
      *(float4*)&slbuf[g][j * 4] = v;
    }
  }
  __syncthreads();
  const int co = t & 7;
  const int nq = t >> 3;  // 0..31, 8 n each
  float acc[8][8];
#pragma unroll
  for (int k = 0; k < 8; ++k)
#pragma unroll
    for (int g = 0; g < 8; ++g) acc[k][g] = 0.f;
#pragma unroll
  for (int jv = 0; jv < 2; ++jv) {
    const int nb = nq * 8 + jv * 4;
    float4 sv[8];
#pragma unroll
    for (int g = 0; g < 8; ++g) sv[g] = *(const float4*)&slbuf[g][nb];
#pragma unroll
    for (int k = 0; k < 8; ++k) {
      float4 xv = *(const float4*)&xs[co + 8 * k][nb];
#pragma unroll
      for (int g = 0; g < 8; ++g) {
        acc[k][g] = fmaf(xv.x, sv[g].x, acc[k][g]);
        acc[k][g] = fmaf(xv.y, sv[g].y, acc[k][g]);
        acc[k][g] = fmaf(xv.z, sv[g].z, acc[k][g]);
        acc[k][g] = fmaf(xv.w, sv[g].w, acc[k][g]);
      }
    }
  }
  // sum the 8 nq-subgroups within each wave -> per-wave 64-n partial
#pragma unroll
  for (int k = 0; k < 8; ++k)
#pragma unroll
    for (int g = 0; g < 8; ++g) {
      float v = acc[k][g];
      v += __shfl_xor(v, 8, 64);
      v += __shfl_xor(v, 16, 64);
      v += __shfl_xor(v, 32, 64);
      acc[k][g] = v;
    }
  __syncthreads();  // all reads of slbuf done; reuse as pool[4][8][8][8]
  float* pool = &slbuf[0][0];
  const int wv = t >> 6, l = t & 63;
  if ((l >> 3) == 0) {
#pragma unroll
    for (int k = 0; k < 8; ++k) {
      *(float4*)&pool[((wv * 8 + l) * 8 + k) * 8 + 0] =
          make_float4(acc[k][0], acc[k][1], acc[k][2], acc[k][3]);
      *(float4*)&pool[((wv * 8 + l) * 8 + k) * 8 + 4] =
          make_float4(acc[k][4], acc[k][5], acc[k][6], acc[k][7]);
    }
  }
  __syncthreads();
  float2 ov;
  float* po = &ov.x;
#pragma unroll
  for (int j = 0; j < 2; ++j) {
    int o = t * 2 + j;
    int cl = o >> 3, g = o & 7;
    int co2 = cl & 7, k2 = cl >> 3;
    po[j] = pool[((0 * 8 + co2) * 8 + k2) * 8 + g] + pool[((1 * 8 + co2) * 8 + k2) * 8 + g] +
            pool[((2 * 8 + co2) * 8 + k2) * 8 + g] + pool[((3 * 8 + co2) * 8 + k2) * 8 + g];
  }
  *(float2*)(simpart + (((size_t)b * 16 + nt) * 256 + c0) * 8 + t * 2) = ov;
}

// ---------------- logits += sim/(xn*sn); !FINAL: also softmax->wg; FINAL: softmax->d_out ----
template <int FINAL>
__global__ __launch_bounds__(256) void k_upd(const float* __restrict__ simpart,
                                             const float* __restrict__ xnorm,
                                             const float* __restrict__ spart2,
                                             float* __restrict__ logits,
                                             float* __restrict__ wg,
                                             float* __restrict__ outw) {
  const int b = blockIdx.x, t = threadIdx.x, c = t;
  __shared__ float snr[8];
  if (t < 8) {
    float s2 = 0.f;
    for (int k = 0; k < 32; ++k) s2 += spart2[((size_t)b * 32 + k) * 8 + t];
    snr[t] = 1.f / fmaxf(sqrtf(s2), EPSF);
  }
  __syncthreads();
  const float xni = 1.f / xnorm[b * 256 + c];
  float* lp = logits + ((size_t)b * 256 + c) * 8;
  float4 l0 = *(const float4*)lp, l1 = *(const float4*)(lp + 4);
  float lg[8] = {l0.x, l0.y, l0.z, l0.w, l1.x, l1.y, l1.z, l1.w};
  float sim[8] = {0, 0, 0, 0, 0, 0, 0, 0};
#pragma unroll 4
  for (int k = 0; k < 16; ++k) {
    const float4* sp = (const float4*)(simpart + (((size_t)b * 16 + k) * 256 + c) * 8);
    float4 a = sp[0], bb = sp[1];
    sim[0] += a.x; sim[1] += a.y; sim[2] += a.z; sim[3] += a.w;
    sim[4] += bb.x; sim[5] += bb.y; sim[6] += bb.z; sim[7] += bb.w;
  }
#pragma unroll
  for (int g = 0; g < 8; ++g) lg[g] += sim[g] * xni * snr[g];
  if (!FINAL) {
    *(float4*)lp = make_float4(lg[0], lg[1], lg[2], lg[3]);
    *(float4*)(lp + 4) = make_float4(lg[4], lg[5], lg[6], lg[7]);
  }
  // softmax
  float m = lg[0];
#pragma unroll
  for (int g = 1; g < 8; ++g) m = fmaxf(m, lg[g]);
  float sum = 0.f;
#pragma unroll
  for (int g = 0; g < 8; ++g) { lg[g] = __expf(lg[g] - m); sum += lg[g]; }
  float r = 1.f / sum;
  float* dst = FINAL ? outw : wg;
  float4* op = (float4*)(dst + ((size_t)b * 256 + c) * 8);
  op[0] = make_float4(lg[0] * r, lg[1] * r, lg[2] * r, lg[3] * r);
  op[1] = make_float4(lg[4] * r, lg[5] * r, lg[6] * r, lg[7] * r);
}

extern "C" void kernel_launch(void* const* d_in, const int* in_sizes, int n_in,
                              void* d_out, int out_size, void* d_ws, size_t ws_size,
                              hipStream_t stream) {
  const float* x = (const float*)d_in[0];
  const float* ga = (const float*)d_in[1];
  const float* conv_w = (const float*)d_in[2];
  const float* conv_b = (const float*)d_in[3];
  const float* lin_w = (const float*)d_in[4];
  const float* lin_b = (const float*)d_in[5];
  float* out = (float*)d_out;
  float* outx = out + 32768;  // x passthrough region

  float* ws = (float*)d_ws;
  float* wT = ws;                   // 16384
  float* pooledpart = ws + 16384;   // 65536
  float* logits = ws + 81920;       // 32768
  float* wg = ws + 114688;          // 32768
  float* xnorm = ws + 147456;       // 4096
  float* s = ws + 151552;           // 524288
  float* spart2 = ws + 675840;      // 4096
  float* simpart = ws + 679936;     // 524288  (end: 1204224 floats ~4.6MB)

  k_wt<<<64, 256, 0, stream>>>(conv_w, wT);
  k_conv<<<1024, 256, 0, stream>>>(x, wT, conv_b, pooledpart, outx);
  k_xnorm<<<4096, 256, 0, stream>>>(x, xnorm);
  k_logits<<<16, 256, 0, stream>>>(pooledpart, lin_w, lin_b, ga, logits, wg);

  // iteration 1
  k_s<<<512, 256, 0, stream>>>(x, wg, s, spart2);
  k_sim<<<1024, 256, 0, stream>>>(x, s, simpart);
  k_upd<0><<<16, 256, 0, stream>>>(simpart, xnorm, spart2, logits, wg, out);

  // iteration 2 (+ final softmax into d_out)
  k_s<<<512, 256, 0, stream>>>(x, wg, s, spart2);
  k_sim<<<1024, 256, 0, stream>>>(x, s, simpart);
  k_upd<1><<<16, 256, 0, stream>>>(simpart, xnorm, spart2, logits, wg, out);
}

// Round 3
// 157.519 us; speedup vs baseline: 1.5702x; 1.5702x over previous
//
#include <hip/hip_runtime.h>

#define BB 16
#define CC 256
#define NN 4096
#define CN (CC*NN)
#define GG 8
#define EPSF 1e-8f

// ---------------- transpose conv_w -> wT[c][d] -----------------------------------------------
__global__ __launch_bounds__(256) void k_wt(const float* __restrict__ conv_w,
                                            float* __restrict__ wT) {
  int o = blockIdx.x * 256 + threadIdx.x;  // 16384
  int d = o >> 8, c = o & 255;
  wT[c * 64 + d] = conv_w[d * 256 + c];
}

// ---------------- x passthrough copy + row norms (fused) -------------------------------------
// grid: 4096 = one block per (b,c) row of 4096 floats. Pure streaming + sumsq reduce.
__global__ __launch_bounds__(256) void k_copy_norm(const float* __restrict__ x,
                                                   float* __restrict__ xout,
                                                   float* __restrict__ xnorm) {
  const int bc = blockIdx.x;
  const int t = threadIdx.x;
  const float4* xr = (const float4*)(x + (size_t)bc * NN);
  float4* xw = (float4*)(xout + (size_t)bc * NN);
  float s = 0.f;
  float4 v0 = xr[t], v1 = xr[t + 256], v2 = xr[t + 512], v3 = xr[t + 768];
  xw[t] = v0; xw[t + 256] = v1; xw[t + 512] = v2; xw[t + 768] = v3;
  s += v0.x * v0.x + v0.y * v0.y + v0.z * v0.z + v0.w * v0.w;
  s += v1.x * v1.x + v1.y * v1.y + v1.z * v1.z + v1.w * v1.w;
  s += v2.x * v2.x + v2.y * v2.y + v2.z * v2.z + v2.w * v2.w;
  s += v3.x * v3.x + v3.y * v3.y + v3.z * v3.z + v3.w * v3.w;
#pragma unroll
  for (int off = 1; off < 64; off <<= 1) s += __shfl_xor(s, off, 64);
  __shared__ float red[4];
  if ((t & 63) == 0) red[t >> 6] = s;
  __syncthreads();
  if (t == 0) xnorm[bc] = fmaxf(sqrtf(red[0] + red[1] + red[2] + red[3]), EPSF);
}

// ---------------- conv(1x1)+relu+pool partials (READ-ONLY x) --------------------------------
// grid: 16 b x 16 n-chunks(256). block: 256 thr = 64 lanes(4 n each, float4) x 4 d-quarter waves.
// Weights staged in LDS [256][64]; per-c reads are wave-uniform ds_read (broadcast, imm offset).
__global__ __launch_bounds__(256) void k_conv(const float* __restrict__ x,
                                              const float* __restrict__ wT,
                                              const float* __restrict__ conv_b,
                                              float* __restrict__ pooledpart) {
  const int b = blockIdx.x >> 4;
  const int chunk = blockIdx.x & 15;
  const int t = threadIdx.x;
  const int lane = t & 63;
  const int wv = t >> 6;
  const int d0 = wv * 16;
  __shared__ float wls[256 * 64];  // 64 KB
#pragma unroll
  for (int k = 0; k < 16; ++k) {
    int o = k * 1024 + t * 4;
    *(float4*)&wls[o] = *(const float4*)&wT[o];
  }
  __syncthreads();
  const float* xp = x + (size_t)b * CN + chunk * 256 + lane * 4;
  float acc[16][4];
#pragma unroll
  for (int i = 0; i < 16; ++i)
#pragma unroll
    for (int j = 0; j < 4; ++j) acc[i][j] = 0.f;
#pragma unroll 8
  for (int c = 0; c < 256; ++c) {
    float4 xv = *(const float4*)(xp + (size_t)c * NN);
    const float* wc = &wls[c * 64 + d0];  // wave-uniform LDS broadcast
#pragma unroll
    for (int i = 0; i < 16; ++i) {
      float w = wc[i];
      acc[i][0] = fmaf(w, xv.x, acc[i][0]);
      acc[i][1] = fmaf(w, xv.y, acc[i][1]);
      acc[i][2] = fmaf(w, xv.z, acc[i][2]);
      acc[i][3] = fmaf(w, xv.w, acc[i][3]);
    }
  }
  const float* cb = conv_b + d0;
#pragma unroll
  for (int i = 0; i < 16; ++i) {
    float bi = cb[i];
    float h = fmaxf(acc[i][0] + bi, 0.f) + fmaxf(acc[i][1] + bi, 0.f) +
              fmaxf(acc[i][2] + bi, 0.f) + fmaxf(acc[i][3] + bi, 0.f);
#pragma unroll
    for (int off = 1; off < 64; off <<= 1) h += __shfl_xor(h, off, 64);
    acc[i][0] = h;
  }
  if (lane == 0) {
    float* pp = pooledpart + ((size_t)b * 16 + chunk) * 64 + d0;
#pragma unroll
    for (int i = 0; i < 16; ++i) pp[i] = acc[i][0];
  }
}

// ---------------- pooled-reduce + logits + log(ga) + softmax -> wg --------------------------
__global__ __launch_bounds__(256) void k_logits(const float* __restrict__ pooledpart,
                                                const float* __restrict__ lin_w,
                                                const float* __restrict__ lin_b,
                                                const float* __restrict__ ga,
                                                float* __restrict__ logits,
                                                float* __restrict__ wg) {
  const int b = blockIdx.x, t = threadIdx.x;
  __shared__ float ps[64];
  if (t < 64) {
    float s = 0.f;
#pragma unroll
    for (int k = 0; k < 16; ++k) s += pooledpart[((size_t)b * 16 + k) * 64 + t];
    ps[t] = s * (1.f / 4096.f);
  }
  __syncthreads();
  const int c = t;
  float out[8];
#pragma unroll
  for (int g = 0; g < 8; ++g) {
    const float4* wr = (const float4*)(lin_w + ((size_t)c * 8 + g) * 64);
    float s = 0.f;
#pragma unroll
    for (int k4 = 0; k4 < 16; ++k4) {
      float4 wv = wr[k4];
      s += wv.x * ps[k4 * 4] + wv.y * ps[k4 * 4 + 1] + wv.z * ps[k4 * 4 + 2] +
           wv.w * ps[k4 * 4 + 3];
    }
    out[g] = s + lin_b[c * 8 + g] + logf(ga[((size_t)b * 256 + c) * 8 + g] + EPSF);
  }
  float* lp = logits + ((size_t)b * 256 + c) * 8;
  *(float4*)lp = make_float4(out[0], out[1], out[2], out[3]);
  *(float4*)(lp + 4) = make_float4(out[4], out[5], out[6], out[7]);
  float m = out[0];
#pragma unroll
  for (int g = 1; g < 8; ++g) m = fmaxf(m, out[g]);
  float sum = 0.f;
#pragma unroll
  for (int g = 0; g < 8; ++g) { out[g] = __expf(out[g] - m); sum += out[g]; }
  float r = 1.f / sum;
  float4* op = (float4*)(wg + ((size_t)b * 256 + c) * 8);
  op[0] = make_float4(out[0] * r, out[1] * r, out[2] * r, out[3] * r);
  op[1] = make_float4(out[4] * r, out[5] * r, out[6] * r, out[7] * r);
}

// ---------------- s[b][g][n] = sum_c w[b][c][g] * x[b][c][n]  (+ s^2 partials) --------------
__global__ __launch_bounds__(256) void k_s(const float* __restrict__ x,
                                           const float* __restrict__ wg,
                                           float* __restrict__ s,
                                           float* __restrict__ spart2) {
  const int b = blockIdx.x >> 5, nt = blockIdx.x & 31;
  const int t = threadIdx.x;
  const int nl = t & 63;
  const int cq = __builtin_amdgcn_readfirstlane(t >> 6);
  const int n0 = nt * 128;
  float ax[8], ay[8];
#pragma unroll
  for (int g = 0; g < 8; ++g) { ax[g] = 0.f; ay[g] = 0.f; }
  const float* wb = wg + (size_t)b * 2048 + cq * 512;
  const float* xb = x + (size_t)b * CN + (size_t)(cq * 64) * NN + n0 + nl * 2;
#pragma unroll 4
  for (int cc = 0; cc < 64; ++cc) {
    const float2 xv = *(const float2*)(xb + (size_t)cc * NN);
    const float* wc = wb + cc * 8;
#pragma unroll
    for (int g = 0; g < 8; ++g) {
      ax[g] = fmaf(wc[g], xv.x, ax[g]);
      ay[g] = fmaf(wc[g], xv.y, ay[g]);
    }
  }
  __shared__ float part[4][8][128];
#pragma unroll
  for (int g = 0; g < 8; ++g) {
    part[cq][g][nl * 2] = ax[g];
    part[cq][g][nl * 2 + 1] = ay[g];
  }
  __syncthreads();
  float* sb = s + (size_t)b * 8 * NN + n0;
#pragma unroll
  for (int k = 0; k < 2; ++k) {
    int f2 = k * 256 + t;
    int g = f2 >> 6, np = f2 & 63;
    float vx = part[0][g][np * 2] + part[1][g][np * 2] + part[2][g][np * 2] + part[3][g][np * 2];
    float vy = part[0][g][np * 2 + 1] + part[1][g][np * 2 + 1] + part[2][g][np * 2 + 1] +
               part[3][g][np * 2 + 1];
    *(float2*)(sb + (size_t)g * NN + np * 2) = make_float2(vx, vy);
    float s2 = vx * vx + vy * vy;
#pragma unroll
    for (int off = 1; off < 64; off <<= 1) s2 += __shfl_xor(s2, off, 64);
    if ((t & 63) == 0) spart2[((size_t)b * 32 + nt) * 8 + g] = s2;
  }
}

// ---------------- sim partials: simpart[b][nt][c][g] = sum_{n in chunk} x*s ------------------
__global__ __launch_bounds__(256) void k_sim(const float* __restrict__ x,
                                             const float* __restrict__ s,
                                             float* __restrict__ simpart) {
  const int blk = blockIdx.x;
  const int cq = blk & 3, nt = (blk >> 2) & 15, b = blk >> 6;
  const int t = threadIdx.x;
  const int n0 = nt * 256, c0 = cq * 64;
  __shared__ float xs[64][260];
  __shared__ float slbuf[8][260];
  {
    const float* xb = x + (size_t)b * CN + (size_t)c0 * NN + n0;
#pragma unroll
    for (int k = 0; k < 16; ++k) {
      int f = k * 256 + t;
      int r = f >> 6, j = f & 63;
      float4 v = *(const float4*)(xb + (size_t)r * NN + j * 4);
      *(float4*)&xs[r][j * 4] = v;
    }
    const float* sb = s + (size_t)b * 8 * NN + n0;
#pragma unroll
    for (int k = 0; k < 2; ++k) {
      int f = k * 256 + t;
      int g = f >> 6, j = f & 63;
      float4 v = *(const float4*)(sb + (size_t)g * NN + j * 4);
      *(float4*)&slbuf[g][j * 4] = v;
    }
  }
  __syncthreads();
  const int co = t & 7;
  const int nq = t >> 3;
  float acc[8][8];
#pragma unroll
  for (int k = 0; k < 8; ++k)
#pragma unroll
    for (int g = 0; g < 8; ++g) acc[k][g] = 0.f;
#pragma unroll
  for (int jv = 0; jv < 2; ++jv) {
    const int nb = nq * 8 + jv * 4;
    float4 sv[8];
#pragma unroll
    for (int g = 0; g < 8; ++g) sv[g] = *(const float4*)&slbuf[g][nb];
#pragma unroll
    for (int k = 0; k < 8; ++k) {
      float4 xv = *(const float4*)&xs[co + 8 * k][nb];
#pragma unroll
      for (int g = 0; g < 8; ++g) {
        acc[k][g] = fmaf(xv.x, sv[g].x, acc[k][g]);
        acc[k][g] = fmaf(xv.y, sv[g].y, acc[k][g]);
        acc[k][g] = fmaf(xv.z, sv[g].z, acc[k][g]);
        acc[k][g] = fmaf(xv.w, sv[g].w, acc[k][g]);
      }
    }
  }
#pragma unroll
  for (int k = 0; k < 8; ++k)
#pragma unroll
    for (int g = 0; g < 8; ++g) {
      float v = acc[k][g];
      v += __shfl_xor(v, 8, 64);
      v += __shfl_xor(v, 16, 64);
      v += __shfl_xor(v, 32, 64);
      acc[k][g] = v;
    }
  __syncthreads();
  float* pool = &slbuf[0][0];
  const int wv = t >> 6, l = t & 63;
  if ((l >> 3) == 0) {
#pragma unroll
    for (int k = 0; k < 8; ++k) {
      *(float4*)&pool[((wv * 8 + l) * 8 + k) * 8 + 0] =
          make_float4(acc[k][0], acc[k][1], acc[k][2], acc[k][3]);
      *(float4*)&pool[((wv * 8 + l) * 8 + k) * 8 + 4] =
          make_float4(acc[k][4], acc[k][5], acc[k][6], acc[k][7]);
    }
  }
  __syncthreads();
  float2 ov;
  float* po = &ov.x;
#pragma unroll
  for (int j = 0; j < 2; ++j) {
    int o = t * 2 + j;
    int cl = o >> 3, g = o & 7;
    int co2 = cl & 7, k2 = cl >> 3;
    po[j] = pool[((0 * 8 + co2) * 8 + k2) * 8 + g] + pool[((1 * 8 + co2) * 8 + k2) * 8 + g] +
            pool[((2 * 8 + co2) * 8 + k2) * 8 + g] + pool[((3 * 8 + co2) * 8 + k2) * 8 + g];
  }
  *(float2*)(simpart + (((size_t)b * 16 + nt) * 256 + c0) * 8 + t * 2) = ov;
}

// ---------------- logits += sim/(xn*sn); !FINAL: softmax->wg; FINAL: softmax->d_out ---------
template <int FINAL>
__global__ __launch_bounds__(256) void k_upd(const float* __restrict__ simpart,
                                             const float* __restrict__ xnorm,
                                             const float* __restrict__ spart2,
                                             float* __restrict__ logits,
                                             float* __restrict__ wg,
                                             float* __restrict__ outw) {
  const int b = blockIdx.x, t = threadIdx.x, c = t;
  __shared__ float snr[8];
  if (t < 8) {
    float s2 = 0.f;
    for (int k = 0; k < 32; ++k) s2 += spart2[((size_t)b * 32 + k) * 8 + t];
    snr[t] = 1.f / fmaxf(sqrtf(s2), EPSF);
  }
  __syncthreads();
  const float xni = 1.f / xnorm[b * 256 + c];
  float* lp = logits + ((size_t)b * 256 + c) * 8;
  float4 l0 = *(const float4*)lp, l1 = *(const float4*)(lp + 4);
  float lg[8] = {l0.x, l0.y, l0.z, l0.w, l1.x, l1.y, l1.z, l1.w};
  float sim[8] = {0, 0, 0, 0, 0, 0, 0, 0};
#pragma unroll 4
  for (int k = 0; k < 16; ++k) {
    const float4* sp = (const float4*)(simpart + (((size_t)b * 16 + k) * 256 + c) * 8);
    float4 a = sp[0], bb = sp[1];
    sim[0] += a.x; sim[1] += a.y; sim[2] += a.z; sim[3] += a.w;
    sim[4] += bb.x; sim[5] += bb.y; sim[6] += bb.z; sim[7] += bb.w;
  }
#pragma unroll
  for (int g = 0; g < 8; ++g) lg[g] += sim[g] * xni * snr[g];
  if (!FINAL) {
    *(float4*)lp = make_float4(lg[0], lg[1], lg[2], lg[3]);
    *(float4*)(lp + 4) = make_float4(lg[4], lg[5], lg[6], lg[7]);
  }
  float m = lg[0];
#pragma unroll
  for (int g = 1; g < 8; ++g) m = fmaxf(m, lg[g]);
  float sum = 0.f;
#pragma unroll
  for (int g = 0; g < 8; ++g) { lg[g] = __expf(lg[g] - m); sum += lg[g]; }
  float r = 1.f / sum;
  float* dst = FINAL ? outw : wg;
  float4* op = (float4*)(dst + ((size_t)b * 256 + c) * 8);
  op[0] = make_float4(lg[0] * r, lg[1] * r, lg[2] * r, lg[3] * r);
  op[1] = make_float4(lg[4] * r, lg[5] * r, lg[6] * r, lg[7] * r);
}

extern "C" void kernel_launch(void* const* d_in, const int* in_sizes, int n_in,
                              void* d_out, int out_size, void* d_ws, size_t ws_size,
                              hipStream_t stream) {
  const float* x = (const float*)d_in[0];
  const float* ga = (const float*)d_in[1];
  const float* conv_w = (const float*)d_in[2];
  const float* conv_b = (const float*)d_in[3];
  const float* lin_w = (const float*)d_in[4];
  const float* lin_b = (const float*)d_in[5];
  float* out = (float*)d_out;
  float* outx = out + 32768;  // x passthrough region

  float* ws = (float*)d_ws;
  float* wT = ws;                   // 16384
  float* pooledpart = ws + 16384;   // 16384
  float* logits = ws + 32768;       // 32768
  float* wg = ws + 65536;           // 32768
  float* xnorm = ws + 98304;        // 4096
  float* s = ws + 102400;           // 524288
  float* spart2 = ws + 626688;      // 4096
  float* simpart = ws + 630784;     // 524288

  k_wt<<<64, 256, 0, stream>>>(conv_w, wT);
  k_copy_norm<<<4096, 256, 0, stream>>>(x, outx, xnorm);
  k_conv<<<256, 256, 0, stream>>>(x, wT, conv_b, pooledpart);
  k_logits<<<16, 256, 0, stream>>>(pooledpart, lin_w, lin_b, ga, logits, wg);

  // iteration 1
  k_s<<<512, 256, 0, stream>>>(x, wg, s, spart2);
  k_sim<<<1024, 256, 0, stream>>>(x, s, simpart);
  k_upd<0><<<16, 256, 0, stream>>>(simpart, xnorm, spart2, logits, wg, out);

  // iteration 2 (+ final softmax into d_out)
  k_s<<<512, 256, 0, stream>>>(x, wg, s, spart2);
  k_sim<<<1024, 256, 0, stream>>>(x, s, simpart);
  k_upd<1><<<16, 256, 0, stream>>>(simpart, xnorm, spart2, logits, wg, out);
}

// Round 4
// 153.353 us; speedup vs baseline: 1.6128x; 1.0272x over previous
//
#include <hip/hip_runtime.h>

#define BB 16
#define CC 256
#define NN 4096
#define CN (CC*NN)
#define GG 8
#define EPSF 1e-8f
#define NT 64      // n-tile per route block
#define STR 68     // padded LDS row stride (words); 68%4==0 -> 16B-aligned rows

// ---------------- transpose conv_w -> wT[c][d] -----------------------------------------------
__global__ __launch_bounds__(256) void k_wt(const float* __restrict__ conv_w,
                                            float* __restrict__ wT) {
  int o = blockIdx.x * 256 + threadIdx.x;  // 16384
  int d = o >> 8, c = o & 255;
  wT[c * 64 + d] = conv_w[d * 256 + c];
}

// ---------------- conv(1x1)+relu+pool partials (READ-ONLY x) --------------------------------
__global__ __launch_bounds__(256) void k_conv(const float* __restrict__ x,
                                              const float* __restrict__ wT,
                                              const float* __restrict__ conv_b,
                                              float* __restrict__ pooledpart) {
  const int b = blockIdx.x >> 4;
  const int chunk = blockIdx.x & 15;
  const int t = threadIdx.x;
  const int lane = t & 63;
  const int wv = t >> 6;
  const int d0 = wv * 16;
  __shared__ float wls[256 * 64];  // 64 KB
#pragma unroll
  for (int k = 0; k < 16; ++k) {
    int o = k * 1024 + t * 4;
    *(float4*)&wls[o] = *(const float4*)&wT[o];
  }
  __syncthreads();
  const float* xp = x + (size_t)b * CN + chunk * 256 + lane * 4;
  float acc[16][4];
#pragma unroll
  for (int i = 0; i < 16; ++i)
#pragma unroll
    for (int j = 0; j < 4; ++j) acc[i][j] = 0.f;
#pragma unroll 8
  for (int c = 0; c < 256; ++c) {
    float4 xv = *(const float4*)(xp + (size_t)c * NN);
    const float* wc = &wls[c * 64 + d0];  // wave-uniform LDS broadcast
#pragma unroll
    for (int i = 0; i < 16; ++i) {
      float w = wc[i];
      acc[i][0] = fmaf(w, xv.x, acc[i][0]);
      acc[i][1] = fmaf(w, xv.y, acc[i][1]);
      acc[i][2] = fmaf(w, xv.z, acc[i][2]);
      acc[i][3] = fmaf(w, xv.w, acc[i][3]);
    }
  }
  const float* cb = conv_b + d0;
#pragma unroll
  for (int i = 0; i < 16; ++i) {
    float bi = cb[i];
    float h = fmaxf(acc[i][0] + bi, 0.f) + fmaxf(acc[i][1] + bi, 0.f) +
              fmaxf(acc[i][2] + bi, 0.f) + fmaxf(acc[i][3] + bi, 0.f);
#pragma unroll
    for (int off = 1; off < 64; off <<= 1) h += __shfl_xor(h, off, 64);
    acc[i][0] = h;
  }
  if (lane == 0) {
    float* pp = pooledpart + ((size_t)b * 16 + chunk) * 64 + d0;
#pragma unroll
    for (int i = 0; i < 16; ++i) pp[i] = acc[i][0];
  }
}

// ---------------- pooled-reduce + logits + log(ga) + softmax -> wg --------------------------
__global__ __launch_bounds__(256) void k_logits(const float* __restrict__ pooledpart,
                                                const float* __restrict__ lin_w,
                                                const float* __restrict__ lin_b,
                                                const float* __restrict__ ga,
                                                float* __restrict__ logits,
                                                float* __restrict__ wg) {
  const int b = blockIdx.x, t = threadIdx.x;
  __shared__ float ps[64];
  if (t < 64) {
    float s = 0.f;
#pragma unroll
    for (int k = 0; k < 16; ++k) s += pooledpart[((size_t)b * 16 + k) * 64 + t];
    ps[t] = s * (1.f / 4096.f);
  }
  __syncthreads();
  const int c = t;
  float out[8];
#pragma unroll
  for (int g = 0; g < 8; ++g) {
    const float4* wr = (const float4*)(lin_w + ((size_t)c * 8 + g) * 64);
    float s = 0.f;
#pragma unroll
    for (int k4 = 0; k4 < 16; ++k4) {
      float4 wv = wr[k4];
      s += wv.x * ps[k4 * 4] + wv.y * ps[k4 * 4 + 1] + wv.z * ps[k4 * 4 + 2] +
           wv.w * ps[k4 * 4 + 3];
    }
    out[g] = s + lin_b[c * 8 + g] + logf(ga[((size_t)b * 256 + c) * 8 + g] + EPSF);
  }
  float* lp = logits + ((size_t)b * 256 + c) * 8;
  *(float4*)lp = make_float4(out[0], out[1], out[2], out[3]);
  *(float4*)(lp + 4) = make_float4(out[4], out[5], out[6], out[7]);
  float m = out[0];
#pragma unroll
  for (int g = 1; g < 8; ++g) m = fmaxf(m, out[g]);
  float sum = 0.f;
#pragma unroll
  for (int g = 0; g < 8; ++g) { out[g] = __expf(out[g] - m); sum += out[g]; }
  float r = 1.f / sum;
  float4* op = (float4*)(wg + ((size_t)b * 256 + c) * 8);
  op[0] = make_float4(out[0] * r, out[1] * r, out[2] * r, out[3] * r);
  op[1] = make_float4(out[4] * r, out[5] * r, out[6] * r, out[7] * r);
}

// ---------------- fused routing iteration: s-tile + sim partials (x staged once) ------------
// grid: 16 b x 64 n-tiles(64). block 256. LDS x[256][STR].
// WRITE_X: also stream x passthrough + per-c sumsq partials (iteration 1 only).
template <int WRITE_X>
__global__ __launch_bounds__(256) void k_route(const float* __restrict__ x,
                                               const float* __restrict__ wg,
                                               float* __restrict__ xout,
                                               float* __restrict__ xnp,
                                               float* __restrict__ spart2,
                                               float* __restrict__ simpart) {
  const int b = blockIdx.x >> 6;
  const int chunk = blockIdx.x & 63;
  const int t = threadIdx.x;
  const int lane = t & 63, wv = t >> 6;
  __shared__ float xs[256 * STR];        // 69632 B  (reused as pool2 in merge)
  __shared__ float wls[256 * 8];         // 8192 B
  __shared__ float st[8 * STR];          // 2176 B   s tile
  __shared__ float pool[4 * 8 * STR];    // 8704 B   phase-1 per-wave partials

  // stage w[b] (256x8)
  {
    const float4* wsrc = (const float4*)(wg + (size_t)b * 2048);
    *(float4*)&wls[t * 8] = wsrc[t * 2];
    *(float4*)&wls[t * 8 + 4] = wsrc[t * 2 + 1];
  }
  // stage x tile: f = k*256+t -> row r=f>>4 (c), float4-col j=f&15
  const float* xb = x + (size_t)b * CN + chunk * NT;
  float sq[16];
#pragma unroll
  for (int k = 0; k < 16; ++k) {
    int f = k * 256 + t;
    int r = f >> 4, j = f & 15;
    float4 v = *(const float4*)(xb + (size_t)r * NN + j * 4);
    *(float4*)&xs[r * STR + j * 4] = v;
    if (WRITE_X) {
      *(float4*)(xout + (size_t)b * CN + (size_t)r * NN + chunk * NT + j * 4) = v;
      sq[k] = v.x * v.x + v.y * v.y + v.z * v.z + v.w * v.w;
    }
  }
  if (WRITE_X) {
    // rows r = k*16 + (t>>4); the 16 lanes sharing a row are lanes (t&~15)..+15
#pragma unroll
    for (int k = 0; k < 16; ++k) {
      float v = sq[k];
      v += __shfl_xor(v, 1, 64); v += __shfl_xor(v, 2, 64);
      v += __shfl_xor(v, 4, 64); v += __shfl_xor(v, 8, 64);
      sq[k] = v;
    }
    if ((t & 15) == 0) {
      float* xp = xnp + ((size_t)b * 64 + chunk) * 256 + (t >> 4);
#pragma unroll
      for (int k = 0; k < 16; ++k) xp[k * 16] = sq[k];
    }
  }
  __syncthreads();

  // ---- phase 1: per-wave s partial over c-quarter; lane owns n=lane ----
  float sacc[8];
#pragma unroll
  for (int g = 0; g < 8; ++g) sacc[g] = 0.f;
  {
    const int c0 = wv * 64;
#pragma unroll 8
    for (int cc = 0; cc < 64; ++cc) {
      float xv = xs[(c0 + cc) * STR + lane];
      const float* wc = &wls[(c0 + cc) * 8];  // wave-uniform broadcast
#pragma unroll
      for (int g = 0; g < 8; ++g) sacc[g] = fmaf(wc[g], xv, sacc[g]);
    }
#pragma unroll
    for (int g = 0; g < 8; ++g) pool[(wv * 8 + g) * STR + lane] = sacc[g];
  }
  __syncthreads();
  // finalize s-tile + spart2 (sumsq over tile n)
#pragma unroll
  for (int k = 0; k < 2; ++k) {
    int g = (t >> 6) + 4 * k;
    int n = t & 63;
    float v = pool[(0 * 8 + g) * STR + n] + pool[(1 * 8 + g) * STR + n] +
              pool[(2 * 8 + g) * STR + n] + pool[(3 * 8 + g) * STR + n];
    st[g * STR + n] = v;
    float s2 = v * v;
#pragma unroll
    for (int off = 1; off < 64; off <<= 1) s2 += __shfl_xor(s2, off, 64);
    if (n == 0) spart2[((size_t)b * 64 + chunk) * 8 + g] = s2;
  }
  __syncthreads();

  // ---- phase 2: sim partials. thread: co=t&31 (c=co+32k), nq=t>>5 (n in [nq*8,nq*8+8)) ----
  const int co = t & 31;
  const int nq = t >> 5;
  float4 sva[8], svb[8];
#pragma unroll
  for (int g = 0; g < 8; ++g) {
    sva[g] = *(const float4*)&st[g * STR + nq * 8];
    svb[g] = *(const float4*)&st[g * STR + nq * 8 + 4];
  }
  float acc[8][8];
#pragma unroll
  for (int k = 0; k < 8; ++k)
#pragma unroll
    for (int g = 0; g < 8; ++g) acc[k][g] = 0.f;
#pragma unroll
  for (int k = 0; k < 8; ++k) {
    const int c = co + 32 * k;
    float4 xa = *(const float4*)&xs[c * STR + nq * 8];
    float4 xb2 = *(const float4*)&xs[c * STR + nq * 8 + 4];
#pragma unroll
    for (int g = 0; g < 8; ++g) {
      float a = acc[k][g];
      a = fmaf(xa.x, sva[g].x, a);
      a = fmaf(xa.y, sva[g].y, a);
      a = fmaf(xa.z, sva[g].z, a);
      a = fmaf(xa.w, sva[g].w, a);
      a = fmaf(xb2.x, svb[g].x, a);
      a = fmaf(xb2.y, svb[g].y, a);
      a = fmaf(xb2.z, svb[g].z, a);
      a = fmaf(xb2.w, svb[g].w, a);
      acc[k][g] = a;
    }
  }
  // combine nq pairs within wave (lanes l <-> l+32 differ only in nq)
#pragma unroll
  for (int k = 0; k < 8; ++k)
#pragma unroll
    for (int g = 0; g < 8; ++g) acc[k][g] += __shfl_xor(acc[k][g], 32, 64);
  __syncthreads();  // done reading xs/st -> reuse xs as pool2[co][(k*4+wv)*8+g], stride 260
  float* pool2 = xs;
  if (lane < 32) {
#pragma unroll
    for (int k = 0; k < 8; ++k) {
      *(float4*)&pool2[co * 260 + (k * 4 + wv) * 8 + 0] =
          make_float4(acc[k][0], acc[k][1], acc[k][2], acc[k][3]);
      *(float4*)&pool2[co * 260 + (k * 4 + wv) * 8 + 4] =
          make_float4(acc[k][4], acc[k][5], acc[k][6], acc[k][7]);
    }
  }
  __syncthreads();
  // merge over waves: output c = t, g = 0..7
  {
    const int mco = t & 31, mk = t >> 5;
    float4 r0 = make_float4(0.f, 0.f, 0.f, 0.f), r1 = r0;
#pragma unroll
    for (int w = 0; w < 4; ++w) {
      float4 a = *(const float4*)&pool2[mco * 260 + (mk * 4 + w) * 8 + 0];
      float4 bq = *(const float4*)&pool2[mco * 260 + (mk * 4 + w) * 8 + 4];
      r0.x += a.x; r0.y += a.y; r0.z += a.z; r0.w += a.w;
      r1.x += bq.x; r1.y += bq.y; r1.z += bq.z; r1.w += bq.w;
    }
    float* sp = simpart + (((size_t)b * 64 + chunk) * 256 + t) * 8;
    *(float4*)sp = r0;
    *(float4*)(sp + 4) = r1;
  }
}

// ---------------- logits += sim/(xn*sn); !FINAL: softmax->wg (+xnorm calc); FINAL: ->d_out --
template <int FINAL>
__global__ __launch_bounds__(256) void k_upd(const float* __restrict__ simpart,
                                             const float* __restrict__ xnp,
                                             const float* __restrict__ spart2,
                                             float* __restrict__ logits,
                                             float* __restrict__ xnorm,
                                             float* __restrict__ wg,
                                             float* __restrict__ outw) {
  const int b = blockIdx.x, t = threadIdx.x, c = t;
  __shared__ float snr[8];
  if (t < 8) {
    float s2 = 0.f;
    for (int k = 0; k < 64; ++k) s2 += spart2[((size_t)b * 64 + k) * 8 + t];
    snr[t] = 1.f / fmaxf(sqrtf(s2), EPSF);
  }
  float xn;
  if (!FINAL) {
    float sqs = 0.f;
#pragma unroll 8
    for (int k = 0; k < 64; ++k) sqs += xnp[((size_t)b * 64 + k) * 256 + c];
    xn = fmaxf(sqrtf(sqs), EPSF);
    xnorm[b * 256 + c] = xn;
  } else {
    xn = xnorm[b * 256 + c];
  }
  __syncthreads();
  const float xni = 1.f / xn;
  float* lp = logits + ((size_t)b * 256 + c) * 8;
  float4 l0 = *(const float4*)lp, l1 = *(const float4*)(lp + 4);
  float lg[8] = {l0.x, l0.y, l0.z, l0.w, l1.x, l1.y, l1.z, l1.w};
  float sim[8] = {0, 0, 0, 0, 0, 0, 0, 0};
#pragma unroll 4
  for (int k = 0; k < 64; ++k) {
    const float4* sp = (const float4*)(simpart + (((size_t)b * 64 + k) * 256 + c) * 8);
    float4 a = sp[0], bb = sp[1];
    sim[0] += a.x; sim[1] += a.y; sim[2] += a.z; sim[3] += a.w;
    sim[4] += bb.x; sim[5] += bb.y; sim[6] += bb.z; sim[7] += bb.w;
  }
#pragma unroll
  for (int g = 0; g < 8; ++g) lg[g] += sim[g] * xni * snr[g];
  if (!FINAL) {
    *(float4*)lp = make_float4(lg[0], lg[1], lg[2], lg[3]);
    *(float4*)(lp + 4) = make_float4(lg[4], lg[5], lg[6], lg[7]);
  }
  float m = lg[0];
#pragma unroll
  for (int g = 1; g < 8; ++g) m = fmaxf(m, lg[g]);
  float sum = 0.f;
#pragma unroll
  for (int g = 0; g < 8; ++g) { lg[g] = __expf(lg[g] - m); sum += lg[g]; }
  float r = 1.f / sum;
  float* dst = FINAL ? outw : wg;
  float4* op = (float4*)(dst + ((size_t)b * 256 + c) * 8);
  op[0] = make_float4(lg[0] * r, lg[1] * r, lg[2] * r, lg[3] * r);
  op[1] = make_float4(lg[4] * r, lg[5] * r, lg[6] * r, lg[7] * r);
}

extern "C" void kernel_launch(void* const* d_in, const int* in_sizes, int n_in,
                              void* d_out, int out_size, void* d_ws, size_t ws_size,
                              hipStream_t stream) {
  const float* x = (const float*)d_in[0];
  const float* ga = (const float*)d_in[1];
  const float* conv_w = (const float*)d_in[2];
  const float* conv_b = (const float*)d_in[3];
  const float* lin_w = (const float*)d_in[4];
  const float* lin_b = (const float*)d_in[5];
  float* out = (float*)d_out;
  float* outx = out + 32768;  // x passthrough region

  float* ws = (float*)d_ws;
  float* wT = ws;                   // 16384
  float* pooledpart = ws + 16384;   // 16384
  float* logits = ws + 32768;       // 32768
  float* wg = ws + 65536;           // 32768
  float* xnorm = ws + 98304;        // 4096
  float* xnp = ws + 102400;         // 262144
  float* spart2 = ws + 364544;      // 8192
  float* simpart = ws + 372736;     // 2097152  (end ~9.9 MB; ws is 256 MiB)

  k_wt<<<64, 256, 0, stream>>>(conv_w, wT);
  k_conv<<<256, 256, 0, stream>>>(x, wT, conv_b, pooledpart);
  k_logits<<<16, 256, 0, stream>>>(pooledpart, lin_w, lin_b, ga, logits, wg);

  // iteration 1 (also writes x passthrough + xnorm partials)
  k_route<1><<<1024, 256, 0, stream>>>(x, wg, outx, xnp, spart2, simpart);
  k_upd<0><<<16, 256, 0, stream>>>(simpart, xnp, spart2, logits, xnorm, wg, out);

  // iteration 2 (+ final softmax into d_out)
  k_route<0><<<1024, 256, 0, stream>>>(x, wg, outx, xnp, spart2, simpart);
  k_upd<1><<<16, 256, 0, stream>>>(simpart, xnp, spart2, logits, xnorm, wg, out);
}

// Round 5
// 135.517 us; speedup vs baseline: 1.8251x; 1.1316x over previous
//
#include <hip/hip_runtime.h>

#define BB 16
#define CC 256
#define NN 4096
#define CN (CC*NN)
#define GG 8
#define EPSF 1e-8f
#define NT 64      // n-tile per route block
#define STR 68     // padded LDS row stride (words); 68*4=272 B, 16B-aligned rows
#define PSTR 65    // pool stride (odd -> conflict-free b32)

// ---------------- transpose conv_w -> wT[c][d] -----------------------------------------------
__global__ __launch_bounds__(256) void k_wt(const float* __restrict__ conv_w,
                                            float* __restrict__ wT) {
  int o = blockIdx.x * 256 + threadIdx.x;  // 16384
  int d = o >> 8, c = o & 255;
  wT[c * 64 + d] = conv_w[d * 256 + c];
}

// ---------------- conv(1x1)+relu+pool partials ----------------------------------------------
// grid: 16 b x 16 n-chunks(256) x 2 d-halves. block: 64 lanes (4n float4) x 4 waves (8d each).
// LDS 32KB weight stage -> >=4 blocks/CU. x re-read 2x is L2/L3-absorbed.
__global__ __launch_bounds__(256, 4) void k_conv(const float* __restrict__ x,
                                                 const float* __restrict__ wT,
                                                 const float* __restrict__ conv_b,
                                                 float* __restrict__ pooledpart) {
  const int dh = blockIdx.x & 1;
  const int chunk = (blockIdx.x >> 1) & 15;
  const int b = blockIdx.x >> 5;
  const int t = threadIdx.x;
  const int lane = t & 63;
  const int wv = t >> 6;
  const int d0 = dh * 32 + wv * 8;
  __shared__ float wls[256 * 32];  // 32 KB: wls[c][j] = wT[c][dh*32+j]
#pragma unroll
  for (int k = 0; k < 8; ++k) {
    int idx = k * 256 + t;          // 0..2047
    int c = idx >> 3, j4 = (idx & 7) * 4;
    *(float4*)&wls[c * 32 + j4] = *(const float4*)&wT[c * 64 + dh * 32 + j4];
  }
  __syncthreads();
  const float* xp = x + (size_t)b * CN + chunk * 256 + lane * 4;
  float acc[8][4];
#pragma unroll
  for (int i = 0; i < 8; ++i)
#pragma unroll
    for (int j = 0; j < 4; ++j) acc[i][j] = 0.f;
#pragma unroll 8
  for (int c = 0; c < 256; ++c) {
    float4 xv = *(const float4*)(xp + (size_t)c * NN);
    const float* wc = &wls[c * 32 + wv * 8];  // wave-uniform LDS broadcast
#pragma unroll
    for (int i = 0; i < 8; ++i) {
      float w = wc[i];
      acc[i][0] = fmaf(w, xv.x, acc[i][0]);
      acc[i][1] = fmaf(w, xv.y, acc[i][1]);
      acc[i][2] = fmaf(w, xv.z, acc[i][2]);
      acc[i][3] = fmaf(w, xv.w, acc[i][3]);
    }
  }
  const float* cb = conv_b + d0;
#pragma unroll
  for (int i = 0; i < 8; ++i) {
    float bi = cb[i];
    float h = fmaxf(acc[i][0] + bi, 0.f) + fmaxf(acc[i][1] + bi, 0.f) +
              fmaxf(acc[i][2] + bi, 0.f) + fmaxf(acc[i][3] + bi, 0.f);
#pragma unroll
    for (int off = 1; off < 64; off <<= 1) h += __shfl_xor(h, off, 64);
    acc[i][0] = h;
  }
  if (lane == 0) {
    float* pp = pooledpart + ((size_t)b * 16 + chunk) * 64 + d0;
#pragma unroll
    for (int i = 0; i < 8; ++i) pp[i] = acc[i][0];
  }
}

// ---------------- pooled-reduce + logits + log(ga) + softmax -> wg --------------------------
__global__ __launch_bounds__(256) void k_logits(const float* __restrict__ pooledpart,
                                                const float* __restrict__ lin_w,
                                                const float* __restrict__ lin_b,
                                                const float* __restrict__ ga,
                                                float* __restrict__ logits,
                                                float* __restrict__ wg) {
  const int b = blockIdx.x, t = threadIdx.x;
  __shared__ float ps[64];
  if (t < 64) {
    float s = 0.f;
#pragma unroll
    for (int k = 0; k < 16; ++k) s += pooledpart[((size_t)b * 16 + k) * 64 + t];
    ps[t] = s * (1.f / 4096.f);
  }
  __syncthreads();
  const int c = t;
  float out[8];
#pragma unroll
  for (int g = 0; g < 8; ++g) {
    const float4* wr = (const float4*)(lin_w + ((size_t)c * 8 + g) * 64);
    float s = 0.f;
#pragma unroll
    for (int k4 = 0; k4 < 16; ++k4) {
      float4 wv = wr[k4];
      s += wv.x * ps[k4 * 4] + wv.y * ps[k4 * 4 + 1] + wv.z * ps[k4 * 4 + 2] +
           wv.w * ps[k4 * 4 + 3];
    }
    out[g] = s + lin_b[c * 8 + g] + logf(ga[((size_t)b * 256 + c) * 8 + g] + EPSF);
  }
  float* lp = logits + ((size_t)b * 256 + c) * 8;
  *(float4*)lp = make_float4(out[0], out[1], out[2], out[3]);
  *(float4*)(lp + 4) = make_float4(out[4], out[5], out[6], out[7]);
  float m = out[0];
#pragma unroll
  for (int g = 1; g < 8; ++g) m = fmaxf(m, out[g]);
  float sum = 0.f;
#pragma unroll
  for (int g = 0; g < 8; ++g) { out[g] = __expf(out[g] - m); sum += out[g]; }
  float r = 1.f / sum;
  float4* op = (float4*)(wg + ((size_t)b * 256 + c) * 8);
  op[0] = make_float4(out[0] * r, out[1] * r, out[2] * r, out[3] * r);
  op[1] = make_float4(out[4] * r, out[5] * r, out[6] * r, out[7] * r);
}

// ---------------- fused routing iteration: s-tile + sim partials (x staged once) ------------
// grid: 16 b x 64 n-tiles(64). block 256. LDS ~80.1KB -> 2 blocks/CU.
// w read straight from global (wave-uniform -> s_load, L2-resident).
template <int WRITE_X>
__global__ __launch_bounds__(256, 2) void k_route(const float* __restrict__ x,
                                                  const float* __restrict__ wg,
                                                  float* __restrict__ xout,
                                                  float* __restrict__ xnp,
                                                  float* __restrict__ spart2,
                                                  float* __restrict__ simpart) {
  const int b = blockIdx.x >> 6;
  const int chunk = blockIdx.x & 63;
  const int t = threadIdx.x;
  const int lane = t & 63, wv = t >> 6;
  __shared__ float xs[256 * STR];      // 69632 B (reused as pool2 in merge)
  __shared__ float st[8 * STR];        // 2176 B   s tile
  __shared__ float pool[32 * PSTR];    // 8320 B   phase-1 per-wave partials

  // stage x tile: f = k*256+t -> row r=f>>4 (c), float4-col j=f&15
  const float* xb = x + (size_t)b * CN + chunk * NT;
  float sq[16];
#pragma unroll
  for (int k = 0; k < 16; ++k) {
    int f = k * 256 + t;
    int r = f >> 4, j = f & 15;
    float4 v = *(const float4*)(xb + (size_t)r * NN + j * 4);
    *(float4*)&xs[r * STR + j * 4] = v;
    if (WRITE_X) {
      *(float4*)(xout + (size_t)b * CN + (size_t)r * NN + chunk * NT + j * 4) = v;
      sq[k] = v.x * v.x + v.y * v.y + v.z * v.z + v.w * v.w;
    }
  }
  if (WRITE_X) {
#pragma unroll
    for (int k = 0; k < 16; ++k) {
      float v = sq[k];
      v += __shfl_xor(v, 1, 64); v += __shfl_xor(v, 2, 64);
      v += __shfl_xor(v, 4, 64); v += __shfl_xor(v, 8, 64);
      sq[k] = v;
    }
    if ((t & 15) == 0) {
      float* xp = xnp + ((size_t)b * 64 + chunk) * 256 + (t >> 4);
#pragma unroll
      for (int k = 0; k < 16; ++k) xp[k * 16] = sq[k];
    }
  }
  __syncthreads();

  // ---- phase 1: per-wave s partial over c-quarter; lane owns n=lane; w via s_load ----
  {
    const int cq = __builtin_amdgcn_readfirstlane(wv);
    float sacc[8];
#pragma unroll
    for (int g = 0; g < 8; ++g) sacc[g] = 0.f;
    const float* wb = wg + (size_t)b * 2048 + cq * 512;  // uniform -> s_load
    const int c0 = cq * 64;
#pragma unroll 8
    for (int cc = 0; cc < 64; ++cc) {
      float xv = xs[(c0 + cc) * STR + lane];
      const float* wc = wb + cc * 8;
#pragma unroll
      for (int g = 0; g < 8; ++g) sacc[g] = fmaf(wc[g], xv, sacc[g]);
    }
#pragma unroll
    for (int g = 0; g < 8; ++g) pool[(cq * 8 + g) * PSTR + lane] = sacc[g];
  }
  __syncthreads();
  // finalize s-tile + spart2 (sumsq over tile n)
#pragma unroll
  for (int k = 0; k < 2; ++k) {
    int g = (t >> 6) + 4 * k;
    int n = t & 63;
    float v = pool[(0 * 8 + g) * PSTR + n] + pool[(1 * 8 + g) * PSTR + n] +
              pool[(2 * 8 + g) * PSTR + n] + pool[(3 * 8 + g) * PSTR + n];
    st[g * STR + n] = v;
    float s2 = v * v;
#pragma unroll
    for (int off = 1; off < 64; off <<= 1) s2 += __shfl_xor(s2, off, 64);
    if (n == 0) spart2[((size_t)b * 64 + chunk) * 8 + g] = s2;
  }
  __syncthreads();

  // ---- phase 2: sim partials. thread: co=t&31 (c=co+32k), nq=t>>5 (8 n each) ----
  const int co = t & 31;
  const int nq = t >> 5;
  float4 sva[8], svb[8];
#pragma unroll
  for (int g = 0; g < 8; ++g) {
    sva[g] = *(const float4*)&st[g * STR + nq * 8];
    svb[g] = *(const float4*)&st[g * STR + nq * 8 + 4];
  }
  float acc[8][8];
#pragma unroll
  for (int k = 0; k < 8; ++k)
#pragma unroll
    for (int g = 0; g < 8; ++g) acc[k][g] = 0.f;
#pragma unroll
  for (int k = 0; k < 8; ++k) {
    const int c = co + 32 * k;
    float4 xa = *(const float4*)&xs[c * STR + nq * 8];
    float4 xb2 = *(const float4*)&xs[c * STR + nq * 8 + 4];
#pragma unroll
    for (int g = 0; g < 8; ++g) {
      float a = acc[k][g];
      a = fmaf(xa.x, sva[g].x, a);
      a = fmaf(xa.y, sva[g].y, a);
      a = fmaf(xa.z, sva[g].z, a);
      a = fmaf(xa.w, sva[g].w, a);
      a = fmaf(xb2.x, svb[g].x, a);
      a = fmaf(xb2.y, svb[g].y, a);
      a = fmaf(xb2.z, svb[g].z, a);
      a = fmaf(xb2.w, svb[g].w, a);
      acc[k][g] = a;
    }
  }
  // combine nq pairs within wave (lanes l <-> l+32 differ only in nq)
#pragma unroll
  for (int k = 0; k < 8; ++k)
#pragma unroll
    for (int g = 0; g < 8; ++g) acc[k][g] += __shfl_xor(acc[k][g], 32, 64);
  __syncthreads();  // done reading xs/st -> reuse xs as pool2[co][(k*4+wv)*8+g], stride 260
  float* pool2 = xs;
  if (lane < 32) {
#pragma unroll
    for (int k = 0; k < 8; ++k) {
      *(float4*)&pool2[co * 260 + (k * 4 + wv) * 8 + 0] =
          make_float4(acc[k][0], acc[k][1], acc[k][2], acc[k][3]);
      *(float4*)&pool2[co * 260 + (k * 4 + wv) * 8 + 4] =
          make_float4(acc[k][4], acc[k][5], acc[k][6], acc[k][7]);
    }
  }
  __syncthreads();
  // merge over waves: output c = t, g = 0..7
  {
    const int mco = t & 31, mk = t >> 5;
    float4 r0 = make_float4(0.f, 0.f, 0.f, 0.f), r1 = r0;
#pragma unroll
    for (int w = 0; w < 4; ++w) {
      float4 a = *(const float4*)&pool2[mco * 260 + (mk * 4 + w) * 8 + 0];
      float4 bq = *(const float4*)&pool2[mco * 260 + (mk * 4 + w) * 8 + 4];
      r0.x += a.x; r0.y += a.y; r0.z += a.z; r0.w += a.w;
      r1.x += bq.x; r1.y += bq.y; r1.z += bq.z; r1.w += bq.w;
    }
    float* sp = simpart + (((size_t)b * 64 + chunk) * 256 + t) * 8;
    *(float4*)sp = r0;
    *(float4*)(sp + 4) = r1;
  }
}

// ---------------- logits += sim/(xn*sn); !FINAL: softmax->wg (+xnorm); FINAL: ->d_out -------
// grid: 16 b x 16 c-slices(16). Parallel k-reduction of simpart/xnp/spart2.
template <int FINAL>
__global__ __launch_bounds__(256) void k_upd(const float* __restrict__ simpart,
                                             const float* __restrict__ xnp,
                                             const float* __restrict__ spart2,
                                             float* __restrict__ logits,
                                             float* __restrict__ xnorm,
                                             float* __restrict__ wg,
                                             float* __restrict__ outw) {
  const int b = blockIdx.x >> 4;
  const int c0 = (blockIdx.x & 15) * 16;
  const int t = threadIdx.x;
  __shared__ float simld[16][8];
  __shared__ float xnl[16];
  __shared__ float snr8[8];
  // sim k-reduction: pair=(cl,g), kh splits k
  {
    const int pair = t >> 1, kh = t & 1;
    const int cl = pair >> 3, g = pair & 7;
    float sm = 0.f;
    const float* sp = simpart + (((size_t)b * 64 + kh * 32) * 256 + c0 + cl) * 8 + g;
#pragma unroll 8
    for (int k = 0; k < 32; ++k) sm += sp[(size_t)k * 2048];
    sm += __shfl_xor(sm, 1, 64);
    if (kh == 0) simld[cl][g] = sm;
  }
  // xnorm
  {
    const int cl2 = t >> 4, kq = t & 15;
    if (!FINAL) {
      float p = 0.f;
#pragma unroll
      for (int j = 0; j < 4; ++j)
        p += xnp[((size_t)b * 64 + kq + 16 * j) * 256 + c0 + cl2];
      p += __shfl_xor(p, 1, 64); p += __shfl_xor(p, 2, 64);
      p += __shfl_xor(p, 4, 64); p += __shfl_xor(p, 8, 64);
      if (kq == 0) {
        float xn = fmaxf(sqrtf(p), EPSF);
        xnl[cl2] = xn;
        xnorm[b * 256 + c0 + cl2] = xn;
      }
    } else {
      if (kq == 0) xnl[cl2] = xnorm[b * 256 + c0 + cl2];
    }
  }
  // s-norms
  if (t < 64) {
    const int g2 = t >> 3, kq = t & 7;
    float p = 0.f;
#pragma unroll
    for (int j = 0; j < 8; ++j) p += spart2[((size_t)b * 64 + kq + 8 * j) * 8 + g2];
    p += __shfl_xor(p, 1, 64); p += __shfl_xor(p, 2, 64); p += __shfl_xor(p, 4, 64);
    if (kq == 0) snr8[g2] = 1.f / fmaxf(sqrtf(p), EPSF);
  }
  __syncthreads();
  if (t < 16) {
    const int c = c0 + t;
    float* lp = logits + ((size_t)b * 256 + c) * 8;
    float4 l0 = *(const float4*)lp, l1 = *(const float4*)(lp + 4);
    float lg[8] = {l0.x, l0.y, l0.z, l0.w, l1.x, l1.y, l1.z, l1.w};
    const float xni = 1.f / xnl[t];
#pragma unroll
    for (int g = 0; g < 8; ++g) lg[g] += simld[t][g] * xni * snr8[g];
    if (!FINAL) {
      *(float4*)lp = make_float4(lg[0], lg[1], lg[2], lg[3]);
      *(float4*)(lp + 4) = make_float4(lg[4], lg[5], lg[6], lg[7]);
    }
    float m = lg[0];
#pragma unroll
    for (int g = 1; g < 8; ++g) m = fmaxf(m, lg[g]);
    float sum = 0.f;
#pragma unroll
    for (int g = 0; g < 8; ++g) { lg[g] = __expf(lg[g] - m); sum += lg[g]; }
    float r = 1.f / sum;
    float* dst = FINAL ? outw : wg;
    float4* op = (float4*)(dst + ((size_t)b * 256 + c) * 8);
    op[0] = make_float4(lg[0] * r, lg[1] * r, lg[2] * r, lg[3] * r);
    op[1] = make_float4(lg[4] * r, lg[5] * r, lg[6] * r, lg[7] * r);
  }
}

extern "C" void kernel_launch(void* const* d_in, const int* in_sizes, int n_in,
                              void* d_out, int out_size, void* d_ws, size_t ws_size,
                              hipStream_t stream) {
  const float* x = (const float*)d_in[0];
  const float* ga = (const float*)d_in[1];
  const float* conv_w = (const float*)d_in[2];
  const float* conv_b = (const float*)d_in[3];
  const float* lin_w = (const float*)d_in[4];
  const float* lin_b = (const float*)d_in[5];
  float* out = (float*)d_out;
  float* outx = out + 32768;  // x passthrough region

  float* ws = (float*)d_ws;
  float* wT = ws;                   // 16384
  float* pooledpart = ws + 16384;   // 16384
  float* logits = ws + 32768;       // 32768
  float* wg = ws + 65536;           // 32768
  float* xnorm = ws + 98304;        // 4096
  float* xnp = ws + 102400;         // 262144
  float* spart2 = ws + 364544;      // 8192
  float* simpart = ws + 372736;     // 2097152

  k_wt<<<64, 256, 0, stream>>>(conv_w, wT);
  k_conv<<<512, 256, 0, stream>>>(x, wT, conv_b, pooledpart);
  k_logits<<<16, 256, 0, stream>>>(pooledpart, lin_w, lin_b, ga, logits, wg);

  // iteration 1 (also writes x passthrough + xnorm partials)
  k_route<1><<<1024, 256, 0, stream>>>(x, wg, outx, xnp, spart2, simpart);
  k_upd<0><<<256, 256, 0, stream>>>(simpart, xnp, spart2, logits, xnorm, wg, out);

  // iteration 2 (+ final softmax into d_out)
  k_route<0><<<1024, 256, 0, stream>>>(x, wg, outx, xnp, spart2, simpart);
  k_upd<1><<<256, 256, 0, stream>>>(simpart, xnp, spart2, logits, xnorm, wg, out);
}

// Round 6
// 134.726 us; speedup vs baseline: 1.8358x; 1.0059x over previous
//
#include <hip/hip_runtime.h>

#define BB 16
#define CC 256
#define NN 4096
#define CN (CC*NN)
#define GG 8
#define EPSF 1e-8f
#define NT 64      // n-tile per route block
#define STR 68     // padded LDS row stride (words); 68*4=272 B, 16B-aligned rows
#define PSTR 65    // pool stride (odd -> conflict-free b32)

// ---------------- transpose conv_w -> wT[c][d] -----------------------------------------------
__global__ __launch_bounds__(256) void k_wt(const float* __restrict__ conv_w,
                                            float* __restrict__ wT) {
  int o = blockIdx.x * 256 + threadIdx.x;  // 16384
  int d = o >> 8, c = o & 255;
  wT[c * 64 + d] = conv_w[d * 256 + c];
}

// ---------------- conv(1x1)+relu+pool partials ----------------------------------------------
// grid: 16 b x 16 n-chunks(256). block: 1024 thr = 16 waves = (c-quarter cq) x (d-quarter dq).
// x read ONCE (float4/lane); weights in 64KB LDS, wave-uniform ds_read_b128.
// Epilogue: 16-step LDS combine of cq partials -> relu -> pool. 16 waves/CU.
__global__ __launch_bounds__(1024) void k_conv(const float* __restrict__ x,
                                               const float* __restrict__ wT,
                                               const float* __restrict__ conv_b,
                                               float* __restrict__ pooledpart) {
  const int b = blockIdx.x >> 4;
  const int chunk = blockIdx.x & 15;
  const int t = threadIdx.x;
  const int lane = t & 63, wave = t >> 6;   // wave 0..15
  const int cq = wave >> 2, dq = wave & 3;  // c-quarter, d-quarter
  const int d0 = dq * 16;
  __shared__ float wls[256 * 64];  // 64 KB weight stage
  __shared__ float buf[16 * 256];  // 16 KB cq-combine buffer
  __shared__ float buf2[16 * 16];  // pool partials [i][wave]
#pragma unroll
  for (int k = 0; k < 4; ++k) {
    int o = k * 4096 + t * 4;
    *(float4*)&wls[o] = *(const float4*)&wT[o];
  }
  __syncthreads();
  const float* xp = x + (size_t)b * CN + (size_t)(cq * 64) * NN + chunk * 256 + lane * 4;
  float acc[16][4];
#pragma unroll
  for (int i = 0; i < 16; ++i)
#pragma unroll
    for (int j = 0; j < 4; ++j) acc[i][j] = 0.f;
#pragma unroll 8
  for (int cc = 0; cc < 64; ++cc) {
    float4 xv = *(const float4*)(xp + (size_t)cc * NN);
    const float* wc = &wls[(cq * 64 + cc) * 64 + d0];  // wave-uniform broadcast
#pragma unroll
    for (int i = 0; i < 16; ++i) {
      float w = wc[i];
      acc[i][0] = fmaf(w, xv.x, acc[i][0]);
      acc[i][1] = fmaf(w, xv.y, acc[i][1]);
      acc[i][2] = fmaf(w, xv.z, acc[i][2]);
      acc[i][3] = fmaf(w, xv.w, acc[i][3]);
    }
  }
  // epilogue: for each d-offset i, combine 4 cq partials, relu, pool
  const int dqr = t >> 8;      // wave-uniform
  const int n = t & 255;
#pragma unroll
  for (int i = 0; i < 16; ++i) {
    __syncthreads();
    *(float4*)&buf[wave * 256 + lane * 4] =
        make_float4(acc[i][0], acc[i][1], acc[i][2], acc[i][3]);
    __syncthreads();
    float h = buf[(0 * 4 + dqr) * 256 + n] + buf[(1 * 4 + dqr) * 256 + n] +
              buf[(2 * 4 + dqr) * 256 + n] + buf[(3 * 4 + dqr) * 256 + n];
    h = fmaxf(h + conv_b[dqr * 16 + i], 0.f);
#pragma unroll
    for (int off = 1; off < 64; off <<= 1) h += __shfl_xor(h, off, 64);
    if (lane == 0) buf2[i * 16 + wave] = h;
  }
  __syncthreads();
  if (t < 64) {
    const int dqf = t >> 4, ii = t & 15;
    float v = buf2[ii * 16 + dqf * 4 + 0] + buf2[ii * 16 + dqf * 4 + 1] +
              buf2[ii * 16 + dqf * 4 + 2] + buf2[ii * 16 + dqf * 4 + 3];
    pooledpart[((size_t)b * 16 + chunk) * 64 + t] = v;
  }
}

// ---------------- pooled-reduce + logits + log(ga) + softmax -> wg --------------------------
__global__ __launch_bounds__(256) void k_logits(const float* __restrict__ pooledpart,
                                                const float* __restrict__ lin_w,
                                                const float* __restrict__ lin_b,
                                                const float* __restrict__ ga,
                                                float* __restrict__ logits,
                                                float* __restrict__ wg) {
  const int b = blockIdx.x, t = threadIdx.x;
  __shared__ float ps[64];
  if (t < 64) {
    float s = 0.f;
#pragma unroll
    for (int k = 0; k < 16; ++k) s += pooledpart[((size_t)b * 16 + k) * 64 + t];
    ps[t] = s * (1.f / 4096.f);
  }
  __syncthreads();
  const int c = t;
  float out[8];
#pragma unroll
  for (int g = 0; g < 8; ++g) {
    const float4* wr = (const float4*)(lin_w + ((size_t)c * 8 + g) * 64);
    float s = 0.f;
#pragma unroll
    for (int k4 = 0; k4 < 16; ++k4) {
      float4 wv = wr[k4];
      s += wv.x * ps[k4 * 4] + wv.y * ps[k4 * 4 + 1] + wv.z * ps[k4 * 4 + 2] +
           wv.w * ps[k4 * 4 + 3];
    }
    out[g] = s + lin_b[c * 8 + g] + logf(ga[((size_t)b * 256 + c) * 8 + g] + EPSF);
  }
  float* lp = logits + ((size_t)b * 256 + c) * 8;
  *(float4*)lp = make_float4(out[0], out[1], out[2], out[3]);
  *(float4*)(lp + 4) = make_float4(out[4], out[5], out[6], out[7]);
  float m = out[0];
#pragma unroll
  for (int g = 1; g < 8; ++g) m = fmaxf(m, out[g]);
  float sum = 0.f;
#pragma unroll
  for (int g = 0; g < 8; ++g) { out[g] = __expf(out[g] - m); sum += out[g]; }
  float r = 1.f / sum;
  float4* op = (float4*)(wg + ((size_t)b * 256 + c) * 8);
  op[0] = make_float4(out[0] * r, out[1] * r, out[2] * r, out[3] * r);
  op[1] = make_float4(out[4] * r, out[5] * r, out[6] * r, out[7] * r);
}

// ---------------- fused routing iteration: s-tile + sim partials (x staged once) ------------
// grid: 16 b x 64 n-tiles(64). block 256. LDS ~80.1KB -> 2 blocks/CU.
// w read straight from global (wave-uniform -> s_load, L2-resident).
template <int WRITE_X>
__global__ __launch_bounds__(256, 2) void k_route(const float* __restrict__ x,
                                                  const float* __restrict__ wg,
                                                  float* __restrict__ xout,
                                                  float* __restrict__ xnp,
                                                  float* __restrict__ spart2,
                                                  float* __restrict__ simpart) {
  const int b = blockIdx.x >> 6;
  const int chunk = blockIdx.x & 63;
  const int t = threadIdx.x;
  const int lane = t & 63, wv = t >> 6;
  __shared__ float xs[256 * STR];      // 69632 B (reused as pool2 in merge)
  __shared__ float st[8 * STR];        // 2176 B   s tile
  __shared__ float pool[32 * PSTR];    // 8320 B   phase-1 per-wave partials

  // stage x tile: f = k*256+t -> row r=f>>4 (c), float4-col j=f&15
  const float* xb = x + (size_t)b * CN + chunk * NT;
  float sq[16];
#pragma unroll
  for (int k = 0; k < 16; ++k) {
    int f = k * 256 + t;
    int r = f >> 4, j = f & 15;
    float4 v = *(const float4*)(xb + (size_t)r * NN + j * 4);
    *(float4*)&xs[r * STR + j * 4] = v;
    if (WRITE_X) {
      *(float4*)(xout + (size_t)b * CN + (size_t)r * NN + chunk * NT + j * 4) = v;
      sq[k] = v.x * v.x + v.y * v.y + v.z * v.z + v.w * v.w;
    }
  }
  if (WRITE_X) {
#pragma unroll
    for (int k = 0; k < 16; ++k) {
      float v = sq[k];
      v += __shfl_xor(v, 1, 64); v += __shfl_xor(v, 2, 64);
      v += __shfl_xor(v, 4, 64); v += __shfl_xor(v, 8, 64);
      sq[k] = v;
    }
    if ((t & 15) == 0) {
      float* xp = xnp + ((size_t)b * 64 + chunk) * 256 + (t >> 4);
#pragma unroll
      for (int k = 0; k < 16; ++k) xp[k * 16] = sq[k];
    }
  }
  __syncthreads();

  // ---- phase 1: per-wave s partial over c-quarter; lane owns n=lane; w via s_load ----
  {
    const int cq = __builtin_amdgcn_readfirstlane(wv);
    float sacc[8];
#pragma unroll
    for (int g = 0; g < 8; ++g) sacc[g] = 0.f;
    const float* wb = wg + (size_t)b * 2048 + cq * 512;  // uniform -> s_load
    const int c0 = cq * 64;
#pragma unroll 8
    for (int cc = 0; cc < 64; ++cc) {
      float xv = xs[(c0 + cc) * STR + lane];
      const float* wc = wb + cc * 8;
#pragma unroll
      for (int g = 0; g < 8; ++g) sacc[g] = fmaf(wc[g], xv, sacc[g]);
    }
#pragma unroll
    for (int g = 0; g < 8; ++g) pool[(cq * 8 + g) * PSTR + lane] = sacc[g];
  }
  __syncthreads();
  // finalize s-tile + spart2 (sumsq over tile n)
#pragma unroll
  for (int k = 0; k < 2; ++k) {
    int g = (t >> 6) + 4 * k;
    int n = t & 63;
    float v = pool[(0 * 8 + g) * PSTR + n] + pool[(1 * 8 + g) * PSTR + n] +
              pool[(2 * 8 + g) * PSTR + n] + pool[(3 * 8 + g) * PSTR + n];
    st[g * STR + n] = v;
    float s2 = v * v;
#pragma unroll
    for (int off = 1; off < 64; off <<= 1) s2 += __shfl_xor(s2, off, 64);
    if (n == 0) spart2[((size_t)b * 64 + chunk) * 8 + g] = s2;
  }
  __syncthreads();

  // ---- phase 2: sim partials. thread: co=t&31 (c=co+32k), nq=t>>5 (8 n each) ----
  const int co = t & 31;
  const int nq = t >> 5;
  float4 sva[8], svb[8];
#pragma unroll
  for (int g = 0; g < 8; ++g) {
    sva[g] = *(const float4*)&st[g * STR + nq * 8];
    svb[g] = *(const float4*)&st[g * STR + nq * 8 + 4];
  }
  float acc[8][8];
#pragma unroll
  for (int k = 0; k < 8; ++k)
#pragma unroll
    for (int g = 0; g < 8; ++g) acc[k][g] = 0.f;
#pragma unroll
  for (int k = 0; k < 8; ++k) {
    const int c = co + 32 * k;
    float4 xa = *(const float4*)&xs[c * STR + nq * 8];
    float4 xb2 = *(const float4*)&xs[c * STR + nq * 8 + 4];
#pragma unroll
    for (int g = 0; g < 8; ++g) {
      float a = acc[k][g];
      a = fmaf(xa.x, sva[g].x, a);
      a = fmaf(xa.y, sva[g].y, a);
      a = fmaf(xa.z, sva[g].z, a);
      a = fmaf(xa.w, sva[g].w, a);
      a = fmaf(xb2.x, svb[g].x, a);
      a = fmaf(xb2.y, svb[g].y, a);
      a = fmaf(xb2.z, svb[g].z, a);
      a = fmaf(xb2.w, svb[g].w, a);
      acc[k][g] = a;
    }
  }
  // combine nq pairs within wave (lanes l <-> l+32 differ only in nq)
#pragma unroll
  for (int k = 0; k < 8; ++k)
#pragma unroll
    for (int g = 0; g < 8; ++g) acc[k][g] += __shfl_xor(acc[k][g], 32, 64);
  __syncthreads();  // done reading xs/st -> reuse xs as pool2[co][(k*4+wv)*8+g], stride 260
  float* pool2 = xs;
  if (lane < 32) {
#pragma unroll
    for (int k = 0; k < 8; ++k) {
      *(float4*)&pool2[co * 260 + (k * 4 + wv) * 8 + 0] =
          make_float4(acc[k][0], acc[k][1], acc[k][2], acc[k][3]);
      *(float4*)&pool2[co * 260 + (k * 4 + wv) * 8 + 4] =
          make_float4(acc[k][4], acc[k][5], acc[k][6], acc[k][7]);
    }
  }
  __syncthreads();
  // merge over waves: output c = t, g = 0..7
  {
    const int mco = t & 31, mk = t >> 5;
    float4 r0 = make_float4(0.f, 0.f, 0.f, 0.f), r1 = r0;
#pragma unroll
    for (int w = 0; w < 4; ++w) {
      float4 a = *(const float4*)&pool2[mco * 260 + (mk * 4 + w) * 8 + 0];
      float4 bq = *(const float4*)&pool2[mco * 260 + (mk * 4 + w) * 8 + 4];
      r0.x += a.x; r0.y += a.y; r0.z += a.z; r0.w += a.w;
      r1.x += bq.x; r1.y += bq.y; r1.z += bq.z; r1.w += bq.w;
    }
    float* sp = simpart + (((size_t)b * 64 + chunk) * 256 + t) * 8;
    *(float4*)sp = r0;
    *(float4*)(sp + 4) = r1;
  }
}

// ---------------- logits += sim/(xn*sn); !FINAL: softmax->wg (+xnorm); FINAL: ->d_out -------
// grid: 16 b x 16 c-slices(16). Parallel k-reduction of simpart/xnp/spart2.
template <int FINAL>
__global__ __launch_bounds__(256) void k_upd(const float* __restrict__ simpart,
                                             const float* __restrict__ xnp,
                                             const float* __restrict__ spart2,
                                             float* __restrict__ logits,
                                             float* __restrict__ xnorm,
                                             float* __restrict__ wg,
                                             float* __restrict__ outw) {
  const int b = blockIdx.x >> 4;
  const int c0 = (blockIdx.x & 15) * 16;
  const int t = threadIdx.x;
  __shared__ float simld[16][8];
  __shared__ float xnl[16];
  __shared__ float snr8[8];
  // sim k-reduction: pair=(cl,g), kh splits k
  {
    const int pair = t >> 1, kh = t & 1;
    const int cl = pair >> 3, g = pair & 7;
    float sm = 0.f;
    const float* sp = simpart + (((size_t)b * 64 + kh * 32) * 256 + c0 + cl) * 8 + g;
#pragma unroll 8
    for (int k = 0; k < 32; ++k) sm += sp[(size_t)k * 2048];
    sm += __shfl_xor(sm, 1, 64);
    if (kh == 0) simld[cl][g] = sm;
  }
  // xnorm
  {
    const int cl2 = t >> 4, kq = t & 15;
    if (!FINAL) {
      float p = 0.f;
#pragma unroll
      for (int j = 0; j < 4; ++j)
        p += xnp[((size_t)b * 64 + kq + 16 * j) * 256 + c0 + cl2];
      p += __shfl_xor(p, 1, 64); p += __shfl_xor(p, 2, 64);
      p += __shfl_xor(p, 4, 64); p += __shfl_xor(p, 8, 64);
      if (kq == 0) {
        float xn = fmaxf(sqrtf(p), EPSF);
        xnl[cl2] = xn;
        xnorm[b * 256 + c0 + cl2] = xn;
      }
    } else {
      if (kq == 0) xnl[cl2] = xnorm[b * 256 + c0 + cl2];
    }
  }
  // s-norms
  if (t < 64) {
    const int g2 = t >> 3, kq = t & 7;
    float p = 0.f;
#pragma unroll
    for (int j = 0; j < 8; ++j) p += spart2[((size_t)b * 64 + kq + 8 * j) * 8 + g2];
    p += __shfl_xor(p, 1, 64); p += __shfl_xor(p, 2, 64); p += __shfl_xor(p, 4, 64);
    if (kq == 0) snr8[g2] = 1.f / fmaxf(sqrtf(p), EPSF);
  }
  __syncthreads();
  if (t < 16) {
    const int c = c0 + t;
    float* lp = logits + ((size_t)b * 256 + c) * 8;
    float4 l0 = *(const float4*)lp, l1 = *(const float4*)(lp + 4);
    float lg[8] = {l0.x, l0.y, l0.z, l0.w, l1.x, l1.y, l1.z, l1.w};
    const float xni = 1.f / xnl[t];
#pragma unroll
    for (int g = 0; g < 8; ++g) lg[g] += simld[t][g] * xni * snr8[g];
    if (!FINAL) {
      *(float4*)lp = make_float4(lg[0], lg[1], lg[2], lg[3]);
      *(float4*)(lp + 4) = make_float4(lg[4], lg[5], lg[6], lg[7]);
    }
    float m = lg[0];
#pragma unroll
    for (int g = 1; g < 8; ++g) m = fmaxf(m, lg[g]);
    float sum = 0.f;
#pragma unroll
    for (int g = 0; g < 8; ++g) { lg[g] = __expf(lg[g] - m); sum += lg[g]; }
    float r = 1.f / sum;
    float* dst = FINAL ? outw : wg;
    float4* op = (float4*)(dst + ((size_t)b * 256 + c) * 8);
    op[0] = make_float4(lg[0] * r, lg[1] * r, lg[2] * r, lg[3] * r);
    op[1] = make_float4(lg[4] * r, lg[5] * r, lg[6] * r, lg[7] * r);
  }
}

extern "C" void kernel_launch(void* const* d_in, const int* in_sizes, int n_in,
                              void* d_out, int out_size, void* d_ws, size_t ws_size,
                              hipStream_t stream) {
  const float* x = (const float*)d_in[0];
  const float* ga = (const float*)d_in[1];
  const float* conv_w = (const float*)d_in[2];
  const float* conv_b = (const float*)d_in[3];
  const float* lin_w = (const float*)d_in[4];
  const float* lin_b = (const float*)d_in[5];
  float* out = (float*)d_out;
  float* outx = out + 32768;  // x passthrough region

  float* ws = (float*)d_ws;
  float* wT = ws;                   // 16384
  float* pooledpart = ws + 16384;   // 16384
  float* logits = ws + 32768;       // 32768
  float* wg = ws + 65536;           // 32768
  float* xnorm = ws + 98304;        // 4096
  float* xnp = ws + 102400;         // 262144
  float* spart2 = ws + 364544;      // 8192
  float* simpart = ws + 372736;     // 2097152

  k_wt<<<64, 256, 0, stream>>>(conv_w, wT);
  k_conv<<<256, 1024, 0, stream>>>(x, wT, conv_b, pooledpart);
  k_logits<<<16, 256, 0, stream>>>(pooledpart, lin_w, lin_b, ga, logits, wg);

  // iteration 1 (also writes x passthrough + xnorm partials)
  k_route<1><<<1024, 256, 0, stream>>>(x, wg, outx, xnp, spart2, simpart);
  k_upd<0><<<256, 256, 0, stream>>>(simpart, xnp, spart2, logits, xnorm, wg, out);

  // iteration 2 (+ final softmax into d_out)
  k_route<0><<<1024, 256, 0, stream>>>(x, wg, outx, xnp, spart2, simpart);
  k_upd<1><<<256, 256, 0, stream>>>(simpart, xnp, spart2, logits, xnorm, wg, out);
}